// Round 1
// baseline (79.841 us; speedup 1.0000x reference)
//
#include <hip/hip_runtime.h>
#include <math.h>

#define N 8192
#define S 32                 // j-slices
#define SLICE (N / S)        // 256 j's per slice == blockDim
#define IBLK 256             // i's per block

// f32 hash pipeline — byte-identical math to the R2-verified version
// (absmax 0.0): i = rint((log512 - log w)/log 1.2), di = 128/1.2^i,
// qx = rint(x/di - 0.5). Fields bounded by input ranges:
//   qx,qy in [0,1035] (11 bits), i,j in [0,23] (5 bits).
// Decimal code qx + qy*1e4 + i*1e8 + j*1e12 is lexicographic in
// (j,i,qy,qx); the 5|5|11|11 bit-pack below is lexicographic in the SAME
// tuple -> equality AND ordering preserved exactly. 32-bit code.
__device__ __forceinline__ unsigned int hash_code32(float x, float y, float w, float h) {
    const float LOG_ALPHA = (float)log((double)1.2f);
    const float LOGW0     = (float)log(512.0);
    float i_f = rintf((LOGW0 - (float)log((double)w)) / LOG_ALPHA);
    float j_f = rintf((LOGW0 - (float)log((double)h)) / LOG_ALPHA);
    float pi  = (float)pow((double)1.2f, (double)i_f);
    float pj  = (float)pow((double)1.2f, (double)j_f);
    float qx  = rintf(x / (128.0f / pi) - 0.5f);
    float qy  = rintf(y / (128.0f / pj) - 0.5f);
    return (unsigned int)qx
         | ((unsigned int)qy  << 11)
         | ((unsigned int)i_f << 22)
         | ((unsigned int)j_f << 27);
}

// K1: v64[i] = code32<<32 | conf_bits  (conf >= 0 -> bits order-monotone).
// Zero lose/rank/out (out=0 also covers the unique-fill columns -> argmax 0).
__global__ void k_codes(const float4* __restrict__ rects,
                        const float* __restrict__ conf,
                        unsigned long long* __restrict__ v64,
                        int* __restrict__ lose,
                        int* __restrict__ rank,
                        int* __restrict__ out) {
    int t = blockIdx.x * blockDim.x + threadIdx.x;
    float4 r = rects[t];
    unsigned int code = hash_code32(r.x, r.y, r.z, r.w);
    v64[t] = ((unsigned long long)code << 32)
           | (unsigned long long)__float_as_uint(conf[t]);
    lose[t] = 0;
    rank[t] = 0;
    out[t]  = 0;
}

// K2: thread (i, slice) scans 256 j's, 2 per ds_read_b128 (8B/pair vs 16B
// before). "j beats i" = same code & higher conf  <=>  me < v_j <= me|0xFFFFFFFF;
// exact conf tie -> smaller index wins (explicit v==me && j<i check).
// LDS reads are wave-uniform broadcasts (conflict-free).
__global__ void __launch_bounds__(IBLK)
k_winner(const unsigned long long* __restrict__ v64, int* __restrict__ lose) {
    __shared__ __align__(16) unsigned long long s_v[SLICE];
    int t  = threadIdx.x;
    int i  = blockIdx.x * IBLK + t;
    int jb = blockIdx.y * SLICE;
    s_v[t] = v64[jb + t];
    unsigned long long me = v64[i];
    unsigned long long hi = me | 0xFFFFFFFFULL;
    __syncthreads();
    const ulonglong2* s2 = (const ulonglong2*)s_v;
    int l = 0;
    #pragma unroll 8
    for (int k = 0; k < SLICE / 2; ++k) {
        ulonglong2 p = s2[k];
        int j0 = jb + 2 * k;
        l |= (int)((p.x > me) & (p.x <= hi));
        l |= (int)((p.x == me) & (j0 < i));
        l |= (int)((p.y > me) & (p.y <= hi));
        l |= (int)((p.y == me) & (j0 + 1 < i));
    }
    if (l) atomicOr(&lose[i], 1);
}

// K3: rank_i += #{j in slice : win_j && code_j < code_i}. Entry is a u32:
// winners carry code32, losers the sentinel 0xFFFFFFFF (max real code is
// ~0xBE...... so the sentinel never counts). 4 pairs per ds_read_b128.
__global__ void __launch_bounds__(IBLK)
k_rank(const unsigned long long* __restrict__ v64,
       const int* __restrict__ lose, int* __restrict__ rank) {
    __shared__ __align__(16) unsigned int s_wc[SLICE];
    int t  = threadIdx.x;
    int i  = blockIdx.x * IBLK + t;
    int jb = blockIdx.y * SLICE + t;
    s_wc[t] = lose[jb] ? 0xFFFFFFFFu : (unsigned int)(v64[jb] >> 32);
    unsigned int ci = (unsigned int)(v64[i] >> 32);
    __syncthreads();
    const uint4* s4 = (const uint4*)s_wc;
    int r = 0;
    #pragma unroll 8
    for (int k = 0; k < SLICE / 4; ++k) {
        uint4 c = s4[k];
        r += (int)(c.x < ci) + (int)(c.y < ci)
           + (int)(c.z < ci) + (int)(c.w < ci);
    }
    if (r) atomicAdd(&rank[i], r);
}

// K4: winners scatter their index at their unique-rank slot.
// conf==0 edge: all-zero score column -> reference argmax returns 0.
__global__ void k_scatter(const float* __restrict__ conf,
                          const int* __restrict__ lose,
                          const int* __restrict__ rank,
                          int* __restrict__ out) {
    int i = blockIdx.x * blockDim.x + threadIdx.x;
    if (lose[i] == 0) {
        out[rank[i]] = (conf[i] == 0.0f) ? 0 : i;
    }
}

extern "C" void kernel_launch(void* const* d_in, const int* in_sizes, int n_in,
                              void* d_out, int out_size, void* d_ws, size_t ws_size,
                              hipStream_t stream) {
    const float4* rects = (const float4*)d_in[0];   // (8192, 4) f32
    const float*  conf  = (const float*)d_in[1];    // (8192,)  f32
    int* out = (int*)d_out;                         // int32 indices

    char* ws = (char*)d_ws;
    unsigned long long* v64 = (unsigned long long*)ws;        // 64 KiB
    int* lose = (int*)(ws + N * 8);                           // 32 KiB
    int* rank = (int*)(ws + N * 8 + N * 4);                   // 32 KiB

    k_codes  <<<N / 256, 256, 0, stream>>>(rects, conf, v64, lose, rank, out);
    k_winner <<<dim3(N / IBLK, S), IBLK, 0, stream>>>(v64, lose);
    k_rank   <<<dim3(N / IBLK, S), IBLK, 0, stream>>>(v64, lose, rank);
    k_scatter<<<N / 256, 256, 0, stream>>>(conf, lose, rank, out);
}